// Round 7
// baseline (314.098 us; speedup 1.0000x reference)
//
#include <hip/hip_runtime.h>

// FinePreprocess: bilinear 8x8 crops of 32-channel feature maps at 2048
// sub-pixel track points per view, 16 views.
//
// features      : (1, 16, 32, 512, 512) f32   -> d_in[0]
// sample_points : (1, 16, 2048, 2)      f32   -> d_in[1]  (x, y), interior
// img_idxs      : (1, 16, 2048)         int   -> d_in[2]  (0..15)
// out           : (1, 16, 2048, 64, 32) f32   -> d_out
//
// R5/R6 lesson: two very different schedules both pinned at ~330us,
// FETCH_SIZE == 828MB, BW 3.3TB/s -> bound by HBM scatter traffic, not
// wave latency. Unique-line footprint is ~450MB; the extra 1.86x is lost
// cross-track line reuse (points sharing a cache line are processed far
// apart). Fix: SPATIAL SORT. Counting-sort tracks by (view, y/32, x/32)
// into d_ws, process in sorted order (perm[]); reuse distance drops from
// ~full-kernel to ~1MB -> L2 absorbs re-touches. Output slot follows the
// track id, so the result is permutation-invariant (deterministic).
// Bijective XCD swizzle keeps each XCD's sorted range in its own L2.
//
// Main kernel body = R6 (two-phase register row window, batched loads,
// contiguous 1KiB nt-stores, masks/clamps dropped: taps provably interior).

#define CROP    8
#define C_CH    32
#define H_DIM   512
#define W_DIM   512
#define HW_SZ   (H_DIM * W_DIM)
#define TPB     4
#define NBX     16          // x bin = x>>5  (32 px)
#define NBY     16          // y bin = y>>5
#define NBUCKET (16 * NBY * NBX)   // 4096

typedef float f32x4 __attribute__((ext_vector_type(4)));

__device__ __forceinline__ int track_key(const float* __restrict__ pts,
                                         const int* __restrict__ bids, int t) {
    const float px = pts[2 * t];
    const float py = pts[2 * t + 1];
    const int   b  = bids[t];
    const int   xb = ((int)px) >> 5;
    const int   yb = ((int)py) >> 5;
    return (b * NBY + yb) * NBX + xb;
}

__global__ void hist_kernel(const float* __restrict__ pts,
                            const int* __restrict__ bids,
                            int* __restrict__ hist, int n) {
    const int t = blockIdx.x * 256 + threadIdx.x;
    if (t >= n) return;
    atomicAdd(&hist[track_key(pts, bids, t)], 1);
}

// Single-wave exclusive scan over NBUCKET=4096 (64 buckets/lane).
__global__ void scan_kernel(const int* __restrict__ hist,
                            int* __restrict__ offs) {
    const int lane = threadIdx.x;          // 0..63
    const int base = lane * (NBUCKET / 64);
    int s = 0;
    for (int i = 0; i < NBUCKET / 64; ++i) s += hist[base + i];
    // exclusive scan of per-lane sums
    int pre = s;
    for (int d = 1; d < 64; d <<= 1) {
        const int v = __shfl_up(pre, d, 64);
        if (lane >= d) pre += v;
    }
    pre -= s;
    int run = pre;
    for (int i = 0; i < NBUCKET / 64; ++i) {
        offs[base + i] = run;
        run += hist[base + i];
    }
}

__global__ void scatter_kernel(const float* __restrict__ pts,
                               const int* __restrict__ bids,
                               const int* __restrict__ offs,
                               int* __restrict__ cursor,
                               int* __restrict__ perm, int n) {
    const int t = blockIdx.x * 256 + threadIdx.x;
    if (t >= n) return;
    const int key  = track_key(pts, bids, t);
    const int slot = offs[key] + atomicAdd(&cursor[key], 1);
    perm[slot] = t;
}

__global__ __launch_bounds__(256, 8) void fine_preprocess_kernel(
    const float* __restrict__ feat,   // (16, 32, 512, 512)
    const float* __restrict__ pts,    // (32768, 2)
    const int*   __restrict__ bids,   // (32768,)
    const int*   __restrict__ perm,   // sorted order (or null)
    float*       __restrict__ out,    // (32768, 64, 32)
    int n_tracks)
{
    const int wid  = threadIdx.x >> 6;
    const int lane = threadIdx.x & 63;

    // Bijective XCD swizzle: block bid (dispatched to XCD bid%8) processes
    // sorted position (bid%8)*per + bid/8 -> each XCD sweeps a contiguous
    // sorted (spatially coherent) range through its private L2.
    const int nwg = gridDim.x;
    int sb = blockIdx.x;
    if ((nwg & 7) == 0) {
        const int per = nwg >> 3;
        sb = (sb & 7) * per + (sb >> 3);
    }
    int t = sb * TPB + wid;
    if (t >= n_tracks) return;
    if (perm) t = perm[t];

    const int cx = lane >> 3;          // crop column 0..7
    const int c0 = (lane & 7) << 2;    // channel quad base

    const float px = pts[2 * t];
    const float py = pts[2 * t + 1];
    const int   b  = bids[t];

    // X part: fixed per lane (lin endpoints exact: lin[0]=-4, lin[7]=+4)
    const float linx = (cx == 7) ? 4.0f : fmaf((float)cx, 8.0f / 7.0f, -4.0f);
    const float X   = px + linx;
    const float x0f = floorf(X);
    const float wx  = X - x0f;
    const int   x0  = (int)x0f;

    const int B0 = (int)floorf(py - 4.0f);   // wave-uniform top row

    const float* __restrict__ fp =
        feat + ((size_t)b * C_CH + c0) * HW_SZ + (size_t)B0 * W_DIM + x0;

    float* __restrict__ obase =
        out + (size_t)t * (CROP * CROP * C_CH) + lane * 4;

    float va[6][4], vb[6][4];

    // ---- phase 1: rows B0 .. B0+5, 48 independent loads ----
    #pragma unroll
    for (int j = 0; j < 6; ++j) {
        #pragma unroll
        for (int cc = 0; cc < 4; ++cc) {
            va[j][cc] = fp[j * W_DIM + cc * HW_SZ];
            vb[j][cc] = fp[j * W_DIM + cc * HW_SZ + 1];
        }
    }

#define EMIT(r, ja, jb, wy_) do {                                             \
    const float wy__ = (wy_);                                                 \
    const float w00 = (1.0f - wy__) * (1.0f - wx);                            \
    const float w01 = (1.0f - wy__) * wx;                                     \
    const float w10 = wy__ * (1.0f - wx);                                     \
    const float w11 = wy__ * wx;                                              \
    f32x4 o;                                                                  \
    o.x = fmaf(va[ja][0], w00, fmaf(vb[ja][0], w01,                           \
          fmaf(va[jb][0], w10, vb[jb][0] * w11)));                            \
    o.y = fmaf(va[ja][1], w00, fmaf(vb[ja][1], w01,                           \
          fmaf(va[jb][1], w10, vb[jb][1] * w11)));                            \
    o.z = fmaf(va[ja][2], w00, fmaf(vb[ja][2], w01,                           \
          fmaf(va[jb][2], w10, vb[jb][2] * w11)));                            \
    o.w = fmaf(va[ja][3], w00, fmaf(vb[ja][3], w01,                           \
          fmaf(va[jb][3], w10, vb[jb][3] * w11)));                            \
    __builtin_nontemporal_store(o,                                            \
        reinterpret_cast<f32x4*>(obase + (r) * 256));                         \
} while (0)

    { const float wy = (py - 4.0f) - (float)B0; EMIT(0, 0, 1, wy); }

#define ROW_P1(r, K) do {                                                     \
    const float Y   = py + fmaf((float)(r), 8.0f / 7.0f, -4.0f);              \
    const float y0f = floorf(Y);                                              \
    const float wy  = Y - y0f;                                                \
    if ((int)y0f - B0 == (K)) EMIT(r, (K), (K) + 1, wy);                      \
    else                      EMIT(r, (K) + 1, (K) + 2, wy);                  \
} while (0)

    ROW_P1(1, 1);
    ROW_P1(2, 2);
    ROW_P1(3, 3);

    // ---- phase 2: rows B0+4 .. B0+9 (window shifted by -4) ----
    #pragma unroll
    for (int cc = 0; cc < 4; ++cc) {
        va[0][cc] = va[4][cc]; vb[0][cc] = vb[4][cc];
        va[1][cc] = va[5][cc]; vb[1][cc] = vb[5][cc];
    }
    #pragma unroll
    for (int j = 2; j < 6; ++j) {
        #pragma unroll
        for (int cc = 0; cc < 4; ++cc) {
            va[j][cc] = fp[(j + 4) * W_DIM + cc * HW_SZ];
            vb[j][cc] = fp[(j + 4) * W_DIM + cc * HW_SZ + 1];
        }
    }

#define ROW_P2(r, K) do {                                                     \
    const float Y   = py + fmaf((float)(r), 8.0f / 7.0f, -4.0f);              \
    const float y0f = floorf(Y);                                              \
    const float wy  = Y - y0f;                                                \
    if ((int)y0f - B0 == (K) + 4) EMIT(r, (K), (K) + 1, wy);                  \
    else                          EMIT(r, (K) + 1, (K) + 2, wy);              \
} while (0)

    ROW_P2(4, 0);
    ROW_P2(5, 1);
    ROW_P2(6, 2);

    { const float wy = (py + 4.0f) - (float)(B0 + 8); EMIT(7, 4, 5, wy); }
}

extern "C" void kernel_launch(void* const* d_in, const int* in_sizes, int n_in,
                              void* d_out, int out_size, void* d_ws, size_t ws_size,
                              hipStream_t stream) {
    const float* feat = (const float*)d_in[0];
    const float* pts  = (const float*)d_in[1];
    const int*   bids = (const int*)d_in[2];
    float*       out  = (float*)d_out;

    const int n_tracks = in_sizes[2];   // 32768
    const int blocks   = (n_tracks + TPB - 1) / TPB;

    // ws layout: hist[NBUCKET] | cursor[NBUCKET] | offs[NBUCKET] | perm[n]
    const size_t need = (size_t)(3 * NBUCKET + n_tracks) * sizeof(int);
    const int* perm = nullptr;

    if (ws_size >= need) {
        int* hist   = (int*)d_ws;
        int* cursor = hist + NBUCKET;
        int* offs   = cursor + NBUCKET;
        int* permw  = offs + NBUCKET;

        hipMemsetAsync(hist, 0, 2 * NBUCKET * sizeof(int), stream);
        hist_kernel<<<(n_tracks + 255) / 256, 256, 0, stream>>>(
            pts, bids, hist, n_tracks);
        scan_kernel<<<1, 64, 0, stream>>>(hist, offs);
        scatter_kernel<<<(n_tracks + 255) / 256, 256, 0, stream>>>(
            pts, bids, offs, cursor, permw, n_tracks);
        perm = permw;
    }

    fine_preprocess_kernel<<<blocks, TPB * 64, 0, stream>>>(
        feat, pts, bids, perm, out, n_tracks);
}